// Round 1
// baseline (1936.152 us; speedup 1.0000x reference)
//
#include <hip/hip_runtime.h>

typedef _Float16 half8 __attribute__((ext_vector_type(8)));
typedef float floatx4 __attribute__((ext_vector_type(4)));

#define MFMA16(A,B,C) __builtin_amdgcn_mfma_f32_16x16x32_f16((A),(B),(C),0,0,0)

__device__ __forceinline__ float fast_sig(float x){
  return 1.0f/(1.0f + __builtin_amdgcn_exp2f(-1.4426950408889634f*x));
}
__device__ __forceinline__ float fast_tanh(float x){
  return 1.0f - 2.0f/(1.0f + __builtin_amdgcn_exp2f(2.8853900817779268f*x));
}

// ---------------------------------------------------------------------------
// Batched LSTM, final h only. One block = 32 sequences, 8 waves (512 thr).
// Wave w owns hidden slice [16w,16w+16) for all 4 gates.
// w_hh held as MFMA B-fragments in VGPRs; h round-trips LDS as f16.
// ---------------------------------------------------------------------------
__global__ __launch_bounds__(512, 2) void lstm_mfma(
    const float* __restrict__ x,      // [N, T, 7]
    const float* __restrict__ w_ih,   // [512, 7]
    const float* __restrict__ w_hh,   // [512, 128]
    const float* __restrict__ b_ih,
    const float* __restrict__ b_hh,
    float* __restrict__ h_out32,      // [N,128] or null
    _Float16* __restrict__ h_out16,   // [N,128] or null
    int T)
{
  __shared__ _Float16 h_lds[32][136];     // 136 f16 = 272B row stride (16B aligned)
  __shared__ float    x_lds[32*140];
  __shared__ float    wih_lds[512*7];
  __shared__ float    bias_lds[512];

  const int tid  = threadIdx.x;
  const int wv   = tid >> 6;
  const int lane = tid & 63;
  const int q    = lane >> 4;
  const int cb   = lane & 15;
  const long base = (long)blockIdx.x * 32;
  const int TF = T*7;

  for (int i = tid; i < 32*TF; i += 512) x_lds[(i/TF)*140 + (i%TF)] = x[base*TF + i];
  for (int i = tid; i < 512*7; i += 512) wih_lds[i] = w_ih[i];
  for (int i = tid; i < 512;   i += 512) bias_lds[i] = b_ih[i] + b_hh[i];
  for (int i = tid; i < 32*136; i += 512) ((_Float16*)h_lds)[i] = (_Float16)0.f;

  // B fragments: bfrag[g][kc][j] = w_hh[col_g][kc*32 + 8q + j]
  half8 bfrag[4][4];
  int col[4];
  for (int g=0; g<4; ++g){
    col[g] = g*128 + wv*16 + cb;
    for (int kc=0; kc<4; ++kc){
      const float* src = w_hh + (long)col[g]*128 + kc*32 + q*8;
      half8 f;
      #pragma unroll
      for (int j=0;j<8;++j) f[j] = (_Float16)src[j];
      bfrag[g][kc] = f;
    }
  }
  __syncthreads();

  float wcol[4][7], bias_g[4];
  for (int g=0; g<4; ++g){
    bias_g[g] = bias_lds[col[g]];
    #pragma unroll
    for (int f=0; f<7; ++f) wcol[g][f] = wih_lds[col[g]*7+f];
  }

  float c_reg[8] = {0,0,0,0,0,0,0,0};
  float h_new[8] = {0,0,0,0,0,0,0,0};

  for (int t=0; t<T; ++t){
    floatx4 acc[4][2];
    #pragma unroll
    for (int mt=0; mt<2; ++mt)
      #pragma unroll
      for (int r=0; r<4; ++r){
        int row = mt*16 + q*4 + r;
        const float* xp = &x_lds[row*140 + t*7];
        float x0=xp[0],x1=xp[1],x2=xp[2],x3=xp[3],x4=xp[4],x5=xp[5],x6=xp[6];
        #pragma unroll
        for (int g=0; g<4; ++g){
          acc[g][mt][r] = bias_g[g]
            + wcol[g][0]*x0 + wcol[g][1]*x1 + wcol[g][2]*x2 + wcol[g][3]*x3
            + wcol[g][4]*x4 + wcol[g][5]*x5 + wcol[g][6]*x6;
        }
      }
    #pragma unroll
    for (int kc=0; kc<4; ++kc){
      half8 a0 = *(const half8*)&h_lds[cb][kc*32 + q*8];
      half8 a1 = *(const half8*)&h_lds[16+cb][kc*32 + q*8];
      #pragma unroll
      for (int g=0; g<4; ++g){
        acc[g][0] = MFMA16(a0, bfrag[g][kc], acc[g][0]);
        acc[g][1] = MFMA16(a1, bfrag[g][kc], acc[g][1]);
      }
    }
    #pragma unroll
    for (int mt=0; mt<2; ++mt)
      #pragma unroll
      for (int r=0; r<4; ++r){
        int idx = mt*4+r;
        float ig = fast_sig(acc[0][mt][r]);
        float fg = fast_sig(acc[1][mt][r]);
        float gg = fast_tanh(acc[2][mt][r]);
        float og = fast_sig(acc[3][mt][r]);
        float c  = fg*c_reg[idx] + ig*gg;
        c_reg[idx] = c;
        h_new[idx] = og*fast_tanh(c);
      }
    __syncthreads();     // all waves done reading h_lds(t-1)
    {
      int hcol = wv*16 + cb;
      #pragma unroll
      for (int mt=0; mt<2; ++mt)
        #pragma unroll
        for (int r=0; r<4; ++r)
          h_lds[mt*16 + q*4 + r][hcol] = (_Float16)h_new[mt*4+r];
    }
    __syncthreads();     // h(t) visible
  }

  {
    int hcol = wv*16 + cb;
    #pragma unroll
    for (int mt=0; mt<2; ++mt)
      #pragma unroll
      for (int r=0; r<4; ++r){
        long row = base + mt*16 + q*4 + r;
        float v = h_new[mt*4+r];
        if (h_out32) h_out32[row*128 + hcol] = v;
        if (h_out16) h_out16[row*128 + hcol] = (_Float16)v;
      }
  }
}

// ---------------------------------------------------------------------------
// Prep: transpose conv weights to [tap][ci][cout] f16; background conv2 field
// v2bg[c2][cell] for uniform relu(b1) input; bgmax over unaffected cells.
// ---------------------------------------------------------------------------
__global__ void prep_kernel(const float* __restrict__ w1, const float* __restrict__ b1,
                            const float* __restrict__ w2, const float* __restrict__ b2,
                            _Float16* __restrict__ w1t, _Float16* __restrict__ w2t,
                            float* __restrict__ v2bg, float* __restrict__ bgmax)
{
  const int tid = threadIdx.x;
  const int gid = blockIdx.x*256 + tid;
  const int gstride = gridDim.x*256;
  for (int i = gid; i < 64*128*9; i += gstride){
    int s = i>>13, rem = i&8191, ci = rem>>6, c1 = rem&63;
    w1t[i] = (_Float16)w1[c1*1152 + ci*9 + s];
  }
  for (int i = gid; i < 32*64*9; i += gstride){
    int s = i/2048, rem = i%2048, ci = rem>>5, c2 = rem&31;
    w2t[i] = (_Float16)w2[c2*576 + ci*9 + s];
  }
  if (blockIdx.x == 0){
    __shared__ float S[32*9];
    __shared__ int bgm[32];
    for (int i=tid;i<288;i+=256){
      int c2=i/9, s=i%9;
      float a=0.f;
      for (int ci=0;ci<64;++ci) a += w2[c2*576+ci*9+s]*fmaxf(b1[ci],0.f);
      S[i]=a;
    }
    if (tid<32) bgm[tid]=0;
    __syncthreads();
    for (int i=tid;i<2048;i+=256){
      int c2=i>>6, cell=i&63, y=cell>>3, xx=cell&7;
      float a=b2[c2];
      for (int dy=0;dy<3;++dy){ int iy=y+dy-1; if((unsigned)iy>7u) continue;
        for (int dx=0;dx<3;++dx){ int ix=xx+dx-1; if((unsigned)ix>7u) continue;
          a += S[c2*9+dy*3+dx]; } }
      v2bg[c2*64+cell]=a;
      bool affected = (y<=3) || (y<=6 && xx>=2 && xx<=6);
      if(!affected) atomicMax(&bgm[c2], __float_as_int(fmaxf(a,0.f)));
    }
    __syncthreads();
    if (tid<32) bgmax[tid]=__int_as_float(bgm[tid]);
  }
}

// ---------------------------------------------------------------------------
// Social pooling + conv stack (sparse) + maxpool + fusion. One block = 1 batch.
// Nonzero grid cells: (0,k+1) k=0..6, (1,0)=nb7, (4,4)=target.
// Conv1 deltas live at 33 cells (rows0-2 all, rows3-5 cols3-5);
// conv2 affected at 47 cells (rows0-3 all, rows4-6 cols2-6); rest = background.
// ---------------------------------------------------------------------------
__global__ __launch_bounds__(256) void social_fuse(
    const float* __restrict__ h_enc, const _Float16* __restrict__ h_nb,
    const _Float16* __restrict__ w1t, const _Float16* __restrict__ w2t,
    const float* __restrict__ b1, const float* __restrict__ v2bg,
    const float* __restrict__ bgmax, const float* __restrict__ fus_w,
    const float* __restrict__ fus_b, float* __restrict__ fused)
{
  __shared__ float vecs[9][128];      // 0..7 neighbors, 8 = target
  __shared__ float d1[33][64];
  __shared__ _Float16 wslice[18432];  // w1 slice (8192) then full w2t (18432)
  __shared__ int pooledI[32];

  const int tid = threadIdx.x;
  const long b = blockIdx.x;

  for (int i=tid;i<1024;i+=256) vecs[i>>7][i&127] = (float)h_nb[(b*8 + (i>>7))*128 + (i&127)];
  for (int i=tid;i<128; i+=256) vecs[8][i] = h_enc[b*128 + i];
  for (int i=tid;i<33*64;i+=256) d1[i>>6][i&63] = 0.f;
  if (tid<32) pooledI[tid] = __float_as_int(bgmax[tid]);

  // conv1 deltas (pre-activation), slice by tap
  for (int s=0;s<9;++s){
    __syncthreads();
    for (int i=tid;i<8192;i+=256) wslice[i] = w1t[s*8192 + i];
    __syncthreads();
    int dy = s/3, dx = s%3;
    for (int it=tid; it<9*64; it+=256){
      int p = it>>6, c1 = it&63;
      int py = (p<7)?0:((p==7)?1:4);
      int px = (p<7)?(p+1):((p==7)?0:4);
      int y = py - dy + 1, xx = px - dx + 1;
      if ((unsigned)y>7u || (unsigned)xx>7u) continue;
      int cell = (y<3) ? y*8+xx : 24 + (y-3)*3 + (xx-3);
      const float* vp = vecs[p];
      float acc = 0.f;
      #pragma unroll 8
      for (int ci=0;ci<128;++ci) acc += (float)wslice[ci*64 + c1] * vp[ci];
      d1[cell][c1] += acc;
    }
  }
  __syncthreads();
  // finalize to post-relu deltas
  for (int i=tid;i<33*64;i+=256){
    int c1 = i&63;
    float bv = b1[c1];
    float bg = fmaxf(bv, 0.f);
    d1[i>>6][c1] = fmaxf(bv + d1[i>>6][c1], 0.f) - bg;
  }
  for (int i=tid;i<18432;i+=256) wslice[i] = w2t[i];
  __syncthreads();

  // conv2 at 47 affected cells + maxpool
  for (int it=tid; it<47*32; it+=256){
    int cell2 = it>>5, c2 = it&31;
    int y  = (cell2<32) ? (cell2>>3) : 4 + (cell2-32)/5;
    int xx = (cell2<32) ? (cell2&7)  : 2 + (cell2-32)%5;
    float acc = v2bg[c2*64 + y*8 + xx];
    for (int dy=0;dy<3;++dy){
      int iy = y+dy-1; if ((unsigned)iy>7u) continue;
      for (int dx=0;dx<3;++dx){
        int ix = xx+dx-1; if ((unsigned)ix>7u) continue;
        int dc;
        if (iy<3) dc = iy*8+ix;
        else if (iy<=5 && ix>=3 && ix<=5) dc = 24+(iy-3)*3+(ix-3);
        else continue;
        const _Float16* wp = &wslice[(dy*3+dx)*2048 + c2];
        const float* dp = d1[dc];
        float a2=0.f;
        #pragma unroll 8
        for (int ci=0;ci<64;++ci) a2 += (float)wp[ci*32] * dp[ci];
        acc += a2;
      }
    }
    acc = fmaxf(acc, 0.f);
    atomicMax(&pooledI[c2], __float_as_int(acc));
  }
  __syncthreads();

  // fusion: tanh(W [h_target; pooled] + b)
  for (int j=tid; j<128; j+=256){
    float a = fus_b[j];
    const float* fw = fus_w + j*160;
    const float* ht = vecs[8];
    #pragma unroll 8
    for (int k=0;k<128;++k) a += fw[k]*ht[k];
    #pragma unroll
    for (int k=0;k<32;++k)  a += fw[128+k]*__int_as_float(pooledI[k]);
    fused[b*128 + j] = fast_tanh(a);
  }
}

// ---------------------------------------------------------------------------
// Decoder: 25 autoregressive steps, pred feedback, out projection.
// Same MFMA structure as lstm_mfma; block = 32 sequences, 512 threads.
// ---------------------------------------------------------------------------
__global__ __launch_bounds__(512, 2) void dec_mfma(
    const float* __restrict__ fused,   // [8192,128]
    const float* __restrict__ w_ih,    // [512,2]
    const float* __restrict__ w_hh,    // [512,128]
    const float* __restrict__ b_ih, const float* __restrict__ b_hh,
    const float* __restrict__ out_w,   // [2,128]
    const float* __restrict__ out_b,   // [2]
    float* __restrict__ out)           // [8192,25,2]
{
  __shared__ _Float16 h_lds[32][136];
  __shared__ float bias_lds[512];
  __shared__ float ow_lds[2][128];
  __shared__ float pred_lds[32][2];

  const int tid  = threadIdx.x;
  const int wv   = tid >> 6;
  const int lane = tid & 63;
  const int q    = lane >> 4;
  const int cb   = lane & 15;
  const long base = (long)blockIdx.x * 32;

  for (int i=tid;i<512;i+=512) bias_lds[i] = b_ih[i] + b_hh[i];
  for (int i=tid;i<256;i+=512) ow_lds[i>>7][i&127] = out_w[i];
  for (int i=tid;i<4096;i+=512) h_lds[i>>7][i&127] = (_Float16)fused[base*128 + i];
  if (tid<64) pred_lds[tid>>1][tid&1] = 0.f;

  half8 bfrag[4][4];
  int col[4];
  for (int g=0; g<4; ++g){
    col[g] = g*128 + wv*16 + cb;
    for (int kc=0; kc<4; ++kc){
      const float* src = w_hh + (long)col[g]*128 + kc*32 + q*8;
      half8 f;
      #pragma unroll
      for (int j=0;j<8;++j) f[j] = (_Float16)src[j];
      bfrag[g][kc] = f;
    }
  }
  float wi0[4], wi1[4];
  for (int g=0; g<4; ++g){ wi0[g] = w_ih[col[g]*2+0]; wi1[g] = w_ih[col[g]*2+1]; }
  float ob0 = out_b[0], ob1 = out_b[1];
  __syncthreads();

  float bias_g[4];
  for (int g=0; g<4; ++g) bias_g[g] = bias_lds[col[g]];

  float c_reg[8] = {0,0,0,0,0,0,0,0};
  float h_new[8];

  for (int t=0; t<25; ++t){
    floatx4 acc[4][2];
    #pragma unroll
    for (int mt=0; mt<2; ++mt)
      #pragma unroll
      for (int r=0; r<4; ++r){
        int row = mt*16 + q*4 + r;
        float p0 = pred_lds[row][0], p1 = pred_lds[row][1];
        #pragma unroll
        for (int g=0; g<4; ++g)
          acc[g][mt][r] = bias_g[g] + wi0[g]*p0 + wi1[g]*p1;
      }
    #pragma unroll
    for (int kc=0; kc<4; ++kc){
      half8 a0 = *(const half8*)&h_lds[cb][kc*32 + q*8];
      half8 a1 = *(const half8*)&h_lds[16+cb][kc*32 + q*8];
      #pragma unroll
      for (int g=0; g<4; ++g){
        acc[g][0] = MFMA16(a0, bfrag[g][kc], acc[g][0]);
        acc[g][1] = MFMA16(a1, bfrag[g][kc], acc[g][1]);
      }
    }
    #pragma unroll
    for (int mt=0; mt<2; ++mt)
      #pragma unroll
      for (int r=0; r<4; ++r){
        int idx = mt*4+r;
        float ig = fast_sig(acc[0][mt][r]);
        float fg = fast_sig(acc[1][mt][r]);
        float gg = fast_tanh(acc[2][mt][r]);
        float og = fast_sig(acc[3][mt][r]);
        float c  = fg*c_reg[idx] + ig*gg;
        c_reg[idx] = c;
        h_new[idx] = og*fast_tanh(c);
      }
    __syncthreads();
    {
      int hcol = wv*16 + cb;
      #pragma unroll
      for (int mt=0; mt<2; ++mt)
        #pragma unroll
        for (int r=0; r<4; ++r)
          h_lds[mt*16 + q*4 + r][hcol] = (_Float16)h_new[mt*4+r];
    }
    __syncthreads();
    // output projection: pair=(m,oc), 8 threads each, shuffle-reduce
    {
      int pair = tid>>3, part = tid&7;
      int m = pair>>1, oc = pair&1;
      const float* owp = ow_lds[oc];
      float v = 0.f;
      #pragma unroll
      for (int k=part*16; k<part*16+16; ++k) v += owp[k]*(float)h_lds[m][k];
      v += __shfl_down(v, 4, 8);
      v += __shfl_down(v, 2, 8);
      v += __shfl_down(v, 1, 8);
      if (part==0){
        v += (oc ? ob1 : ob0);
        pred_lds[m][oc] = v;
        out[(base+m)*50 + t*2 + oc] = v;
      }
    }
    __syncthreads();
  }
}

// ---------------------------------------------------------------------------
extern "C" void kernel_launch(void* const* d_in, const int* in_sizes, int n_in,
                              void* d_out, int out_size, void* d_ws, size_t ws_size,
                              hipStream_t stream)
{
  (void)in_sizes; (void)n_in; (void)out_size; (void)ws_size;
  const float* target   = (const float*)d_in[0];
  const float* neigh    = (const float*)d_in[1];
  const float* enc_w_ih = (const float*)d_in[4];
  const float* enc_w_hh = (const float*)d_in[5];
  const float* enc_b_ih = (const float*)d_in[6];
  const float* enc_b_hh = (const float*)d_in[7];
  const float* nb_w_ih  = (const float*)d_in[8];
  const float* nb_w_hh  = (const float*)d_in[9];
  const float* nb_b_ih  = (const float*)d_in[10];
  const float* nb_b_hh  = (const float*)d_in[11];
  const float* w1       = (const float*)d_in[12];
  const float* b1       = (const float*)d_in[13];
  const float* w2       = (const float*)d_in[14];
  const float* b2       = (const float*)d_in[15];
  const float* fus_w    = (const float*)d_in[16];
  const float* fus_b    = (const float*)d_in[17];
  const float* dec_w_ih = (const float*)d_in[18];
  const float* dec_w_hh = (const float*)d_in[19];
  const float* dec_b_ih = (const float*)d_in[20];
  const float* dec_b_hh = (const float*)d_in[21];
  const float* out_w    = (const float*)d_in[22];
  const float* out_b    = (const float*)d_in[23];

  char* ws = (char*)d_ws;
  float*    h_enc  = (float*)ws;                          // 8192*128*4 = 4 MB
  _Float16* h_nb   = (_Float16*)(ws + (4u<<20));          // 65536*128*2 = 16 MB
  float*    fusedp = (float*)(ws + (20u<<20));            // 4 MB
  char* aux = ws + (24u<<20);
  _Float16* w1t    = (_Float16*)aux;                      // 147456 B
  _Float16* w2t    = (_Float16*)(aux + 147456);           // 36864 B
  float*    v2bg   = (float*)(aux + 147456 + 36864);      // 8192 B
  float*    bgmaxp = (float*)(aux + 147456 + 36864 + 8192);

  prep_kernel<<<64, 256, 0, stream>>>(w1, b1, w2, b2, w1t, w2t, v2bg, bgmaxp);
  lstm_mfma<<<256, 512, 0, stream>>>(target, enc_w_ih, enc_w_hh, enc_b_ih, enc_b_hh,
                                     h_enc, (_Float16*)nullptr, 20);
  lstm_mfma<<<2048, 512, 0, stream>>>(neigh, nb_w_ih, nb_w_hh, nb_b_ih, nb_b_hh,
                                      (float*)nullptr, h_nb, 20);
  social_fuse<<<8192, 256, 0, stream>>>(h_enc, h_nb, w1t, w2t, b1, v2bg, bgmaxp,
                                        fus_w, fus_b, fusedp);
  dec_mfma<<<256, 512, 0, stream>>>(fusedp, dec_w_ih, dec_w_hh, dec_b_ih, dec_b_hh,
                                    out_w, out_b, (float*)d_out);
}

// Round 2
// 1039.523 us; speedup vs baseline: 1.8625x; 1.8625x over previous
//
#include <hip/hip_runtime.h>

typedef _Float16 half8  __attribute__((ext_vector_type(8)));
typedef _Float16 half4v __attribute__((ext_vector_type(4)));
typedef float  floatx4  __attribute__((ext_vector_type(4)));

#define MFMA16(A,B,C) __builtin_amdgcn_mfma_f32_16x16x32_f16((A),(B),(C),0,0,0)

__device__ __forceinline__ float fast_sig(float x){
  return 1.0f/(1.0f + __builtin_amdgcn_exp2f(-1.4426950408889634f*x));
}
__device__ __forceinline__ float fast_tanh(float x){
  return 1.0f - 2.0f/(1.0f + __builtin_amdgcn_exp2f(2.8853900817779268f*x));
}
// 8B-aligned f16x8 load (2x b64) — LDS strides here are 8B- but not 16B-multiples
__device__ __forceinline__ half8 ld8(const _Float16* p){
  half4v a = *(const half4v*)p;
  half4v b = *(const half4v*)(p+4);
  return __builtin_shufflevector(a,b,0,1,2,3,4,5,6,7);
}

// grid geometry tables (compile-time foldable)
static __device__ constexpr int DY[27] = {0,0,0,0,0,0,0,0, 1,1,1,1,1,1,1,1, 2,2, 3,3,3,4,4,4,5,5,5};
static __device__ constexpr int DX[27] = {0,1,2,3,4,5,6,7, 0,1,2,3,4,5,6,7, 0,1, 3,4,5,3,4,5,3,4,5};
static __device__ constexpr int PY[9]  = {0,0,0,0,0,0,0,1,4};
static __device__ constexpr int PX[9]  = {1,2,3,4,5,6,7,0,4};
static __device__ constexpr int OY[46] = {0,0,0,0,0,0,0,0, 1,1,1,1,1,1,1,1, 2,2,2,2,2,2,2,2,
                                          3,3,3,3,3,3,3, 4,4,4,4,4, 5,5,5,5,5, 6,6,6,6,6};
static __device__ constexpr int OX[46] = {0,1,2,3,4,5,6,7, 0,1,2,3,4,5,6,7, 0,1,2,3,4,5,6,7,
                                          0,1,2,3,4,5,6, 2,3,4,5,6, 2,3,4,5,6, 2,3,4,5,6};
__device__ constexpr int d1idx(int iy,int ix){
  return (iy<0||iy>7||ix<0||ix>7) ? -1 :
         (iy<=1) ? iy*8+ix :
         (iy==2 && ix<=1) ? 16+ix :
         (iy>=3 && iy<=5 && ix>=3 && ix<=5) ? 18+(iy-3)*3+(ix-3) : -1;
}

// ---------------------------------------------------------------------------
// Combined encoder: blocks [0,256) = target LSTM, [256,2304) = neighbor LSTM.
// One block = 32 sequences, 8 waves. w_hh as MFMA B-frags in VGPRs.
// ---------------------------------------------------------------------------
__global__ __launch_bounds__(512, 2) void lstm_all(
    const float* __restrict__ target, const float* __restrict__ neigh,
    const float* __restrict__ e_wih, const float* __restrict__ e_whh,
    const float* __restrict__ e_bih, const float* __restrict__ e_bhh,
    const float* __restrict__ n_wih, const float* __restrict__ n_whh,
    const float* __restrict__ n_bih, const float* __restrict__ n_bhh,
    _Float16* __restrict__ h_enc16, _Float16* __restrict__ h_nb16)
{
  __shared__ _Float16 h_lds[32][136];
  __shared__ float    x_lds[32*140];

  const int tid  = threadIdx.x;
  const int wv   = tid >> 6;
  const int lane = tid & 63;
  const int q    = lane >> 4;
  const int cb   = lane & 15;

  const bool enc = (blockIdx.x < 256);
  const float* x   = enc ? target : neigh;
  const float* wih = enc ? e_wih : n_wih;
  const float* whh = enc ? e_whh : n_whh;
  const float* bih = enc ? e_bih : n_bih;
  const float* bhh = enc ? e_bhh : n_bhh;
  _Float16* hout   = enc ? h_enc16 : h_nb16;
  const long base  = enc ? (long)blockIdx.x*32 : (long)(blockIdx.x-256)*32;

  for (int i = tid; i < 32*140; i += 512) x_lds[(i/140)*140 + (i%140)] = x[base*140 + i];
  for (int i = tid; i < 32*136; i += 512) ((_Float16*)h_lds)[i] = (_Float16)0.f;

  half8 bfrag[4][4];
  int col[4];
  float wcol[4][7], bias_g[4];
  for (int g=0; g<4; ++g){
    col[g] = g*128 + wv*16 + cb;
    bias_g[g] = bih[col[g]] + bhh[col[g]];
    #pragma unroll
    for (int f=0; f<7; ++f) wcol[g][f] = wih[col[g]*7+f];
    for (int kc=0; kc<4; ++kc){
      const float* src = whh + (long)col[g]*128 + kc*32 + q*8;
      half8 f;
      #pragma unroll
      for (int j=0;j<8;++j) f[j] = (_Float16)src[j];
      bfrag[g][kc] = f;
    }
  }
  __syncthreads();

  float c_reg[8] = {0,0,0,0,0,0,0,0};
  float h_new[8] = {0,0,0,0,0,0,0,0};

  for (int t=0; t<20; ++t){
    floatx4 acc[4][2];
    #pragma unroll
    for (int mt=0; mt<2; ++mt)
      #pragma unroll
      for (int r=0; r<4; ++r){
        int row = mt*16 + q*4 + r;
        const float* xp = &x_lds[row*140 + t*7];
        float x0=xp[0],x1=xp[1],x2=xp[2],x3=xp[3],x4=xp[4],x5=xp[5],x6=xp[6];
        #pragma unroll
        for (int g=0; g<4; ++g){
          acc[g][mt][r] = bias_g[g]
            + wcol[g][0]*x0 + wcol[g][1]*x1 + wcol[g][2]*x2 + wcol[g][3]*x3
            + wcol[g][4]*x4 + wcol[g][5]*x5 + wcol[g][6]*x6;
        }
      }
    #pragma unroll
    for (int kc=0; kc<4; ++kc){
      half8 a0 = *(const half8*)&h_lds[cb][kc*32 + q*8];
      half8 a1 = *(const half8*)&h_lds[16+cb][kc*32 + q*8];
      #pragma unroll
      for (int g=0; g<4; ++g){
        acc[g][0] = MFMA16(a0, bfrag[g][kc], acc[g][0]);
        acc[g][1] = MFMA16(a1, bfrag[g][kc], acc[g][1]);
      }
    }
    #pragma unroll
    for (int mt=0; mt<2; ++mt)
      #pragma unroll
      for (int r=0; r<4; ++r){
        int idx = mt*4+r;
        float ig = fast_sig(acc[0][mt][r]);
        float fg = fast_sig(acc[1][mt][r]);
        float gg = fast_tanh(acc[2][mt][r]);
        float og = fast_sig(acc[3][mt][r]);
        float c  = fg*c_reg[idx] + ig*gg;
        c_reg[idx] = c;
        h_new[idx] = og*fast_tanh(c);
      }
    __syncthreads();
    {
      int hcol = wv*16 + cb;
      #pragma unroll
      for (int mt=0; mt<2; ++mt)
        #pragma unroll
        for (int r=0; r<4; ++r)
          h_lds[mt*16 + q*4 + r][hcol] = (_Float16)h_new[mt*4+r];
    }
    __syncthreads();
  }

  {
    int hcol = wv*16 + cb;
    #pragma unroll
    for (int mt=0; mt<2; ++mt)
      #pragma unroll
      for (int r=0; r<4; ++r)
        hout[(base + mt*16 + q*4 + r)*128 + hcol] = (_Float16)h_new[mt*4+r];
  }
}

// ---------------------------------------------------------------------------
// Prep: weights into MFMA B-fragment-friendly f16 layouts + conv2 background.
// w1f[s][c1][132] (k=ci contig), w2f[s][c2][68], fus_wf[n][164].
// v2bg[cell][c2]; bgmax[c2] = max relu(v2bg) over cells NOT in the 46-set.
// ---------------------------------------------------------------------------
__global__ void prep_kernel(const float* __restrict__ w1, const float* __restrict__ b1,
                            const float* __restrict__ w2, const float* __restrict__ b2,
                            const float* __restrict__ fus_w,
                            _Float16* __restrict__ w1f, _Float16* __restrict__ w2f,
                            _Float16* __restrict__ fus_wf,
                            float* __restrict__ v2bg, float* __restrict__ bgmax)
{
  const int tid = threadIdx.x;
  const int gid = blockIdx.x*256 + tid;
  const int gstride = gridDim.x*256;
  for (int i = gid; i < 9*64*128; i += gstride){
    int s = i>>13, rem = i&8191, c1 = rem>>7, ci = rem&127;
    w1f[s*8448 + c1*132 + ci] = (_Float16)w1[c1*1152 + ci*9 + s];
  }
  for (int i = gid; i < 9*32*64; i += gstride){
    int s = i>>11, rem = i&2047, c2 = rem>>6, ci = rem&63;
    w2f[s*2176 + c2*68 + ci] = (_Float16)w2[c2*576 + ci*9 + s];
  }
  for (int i = gid; i < 128*160; i += gstride){
    int n = i/160, k = i%160;
    fus_wf[n*164 + k] = (_Float16)fus_w[i];
  }
  if (blockIdx.x == 0){
    __shared__ float S[288];
    __shared__ int bgm[32];
    for (int i=tid;i<288;i+=256){
      int c2=i/9, s=i%9;
      float a=0.f;
      for (int ci=0;ci<64;++ci) a += w2[c2*576+ci*9+s]*fmaxf(b1[ci],0.f);
      S[i]=a;
    }
    if (tid<32) bgm[tid]=0;
    __syncthreads();
    for (int i=tid;i<2048;i+=256){
      int cell=i>>5, c2=i&31, y=cell>>3, xx=cell&7;
      float a=b2[c2];
      for (int dy=0;dy<3;++dy){ int iy=y+dy-1; if((unsigned)iy>7u) continue;
        for (int dx=0;dx<3;++dx){ int ix=xx+dx-1; if((unsigned)ix>7u) continue;
          a += S[c2*9+dy*3+dx]; } }
      v2bg[cell*32+c2]=a;
      bool aff = (y<=2) || (y==3 && xx<=6) || (y>=4 && y<=6 && xx>=2 && xx<=6);
      if(!aff) atomicMax(&bgm[c2], __float_as_int(fmaxf(a,0.f)));
    }
    __syncthreads();
    if (tid<32) bgmax[tid]=__int_as_float(bgm[tid]);
  }
}

// ---------------------------------------------------------------------------
// Social pooling + sparse conv stack + maxpool + fusion, MFMA formulation.
// Block = 16 batch elements (M=16), 256 thr / 4 waves. 512 blocks.
// conv1: wave = c1 n-tile, all 27 delta cells;  conv2: cells split by wave%4;
// fusion: wave = 2 n-tiles of 8. Weights live in VGPRs as B-fragments.
// ---------------------------------------------------------------------------
__global__ __launch_bounds__(256, 1) void social_fuse(
    const _Float16* __restrict__ h_enc, const _Float16* __restrict__ h_nb,
    const _Float16* __restrict__ w1f, const _Float16* __restrict__ w2f,
    const _Float16* __restrict__ fus_wf,
    const float* __restrict__ b1, const float* __restrict__ v2bg,
    const float* __restrict__ bgmax, const float* __restrict__ fus_b,
    float* __restrict__ fused)
{
  __shared__ __align__(16) _Float16 vecs[9*16*132];  // [p][batch][132] 38,016 B
  __shared__ __align__(16) _Float16 d1[27*16*68];    // [cell][batch][68] 58,752 B
  __shared__ __align__(16) _Float16 A16[16*164];     // [batch][h_t(128)|pooled(32)|pad]
  __shared__ int pooled[512];                        // [batch][32]

  const int tid  = threadIdx.x;
  const int wv   = tid >> 6;
  const int lane = tid & 63;
  const int q    = lane >> 4;
  const int cb   = lane & 15;
  const long base = (long)blockIdx.x * 16;

  // ---- stage activations (8B units, coalesced) ----
  for (int i=tid; i<9*16*32; i+=256){
    int p = i>>9, rem = i&511, bb = rem>>5, j = rem&31;
    const _Float16* src = (p<8) ? (h_nb + (((base+bb))*8 + p)*128 + j*4)
                                : (h_enc + (base+bb)*128 + j*4);
    *(unsigned long long*)(vecs + p*2112 + bb*132 + j*4) = *(const unsigned long long*)src;
  }
  for (int i=tid; i<512; i+=256){
    int bb=i>>5, j=i&31;
    *(unsigned long long*)(A16 + bb*164 + j*4) =
        *(const unsigned long long*)(h_enc + (base+bb)*128 + j*4);
  }
  for (int i=tid; i<512; i+=256) pooled[i] = __float_as_int(bgmax[i&31]);
  __syncthreads();

  // ---- conv1: wave wv owns c1 slice [16wv,16wv+16) ----
  {
    const int c1lane = wv*16 + cb;
    half8 bf1[9][4];
    #pragma unroll
    for (int s=0;s<9;++s)
      #pragma unroll
      for (int kc=0;kc<4;++kc)
        bf1[s][kc] = ld8(w1f + s*8448 + c1lane*132 + kc*32 + q*8);
    const float b1v = b1[c1lane];
    const float bg  = fmaxf(b1v, 0.f);

    #pragma unroll
    for (int ci=0; ci<27; ++ci){
      const int y = DY[ci], x = DX[ci];
      floatx4 C = {0.f,0.f,0.f,0.f};
      #pragma unroll
      for (int p=0;p<9;++p){
        const int dy = PY[p]-y+1, dx = PX[p]-x+1;
        if (dy>=0 && dy<3 && dx>=0 && dx<3){
          const int s = dy*3+dx;
          const _Float16* ap = vecs + p*2112 + cb*132 + q*8;
          #pragma unroll
          for (int kc=0;kc<4;++kc)
            C = MFMA16(ld8(ap + kc*32), bf1[s][kc], C);
        }
      }
      _Float16* dp = d1 + ci*1088 + c1lane;
      #pragma unroll
      for (int r=0;r<4;++r)
        dp[(q*4+r)*68] = (_Float16)(fmaxf(b1v + C[r], 0.f) - bg);
    }
  }
  __syncthreads();

  // ---- conv2 + maxpool: out-cells split across waves ----
  {
    half8 bf2[9][2][2];
    #pragma unroll
    for (int s=0;s<9;++s)
      #pragma unroll
      for (int nt=0;nt<2;++nt)
        #pragma unroll
        for (int kc=0;kc<2;++kc)
          bf2[s][nt][kc] = ld8(w2f + s*2176 + (nt*16+cb)*68 + kc*32 + q*8);

    float rm0[4] = {0,0,0,0}, rm1[4] = {0,0,0,0};
    #pragma unroll
    for (int oc=0; oc<46; ++oc){
      if ((oc & 3) != wv) continue;
      const int y = OY[oc], x = OX[oc];
      const int cell = y*8+x;
      float v0 = v2bg[cell*32 + cb];
      float v1 = v2bg[cell*32 + 16 + cb];
      floatx4 C0 = {v0,v0,v0,v0}, C1 = {v1,v1,v1,v1};
      #pragma unroll
      for (int dy=0;dy<3;++dy)
        #pragma unroll
        for (int dx=0;dx<3;++dx){
          const int dc = d1idx(y+dy-1, x+dx-1);
          if (dc < 0) continue;
          const int s = dy*3+dx;
          const _Float16* ap = d1 + dc*1088 + cb*68 + q*8;
          #pragma unroll
          for (int kc=0;kc<2;++kc){
            half8 a = ld8(ap + kc*32);
            C0 = MFMA16(a, bf2[s][0][kc], C0);
            C1 = MFMA16(a, bf2[s][1][kc], C1);
          }
        }
      #pragma unroll
      for (int r=0;r<4;++r){
        rm0[r] = fmaxf(rm0[r], fmaxf(C0[r],0.f));
        rm1[r] = fmaxf(rm1[r], fmaxf(C1[r],0.f));
      }
    }
    #pragma unroll
    for (int r=0;r<4;++r){
      atomicMax(&pooled[(q*4+r)*32 + cb],      __float_as_int(rm0[r]));
      atomicMax(&pooled[(q*4+r)*32 + 16 + cb], __float_as_int(rm1[r]));
    }
  }
  __syncthreads();

  for (int i=tid;i<512;i+=256){
    int bb=i>>5, c2=i&31;
    A16[bb*164 + 128 + c2] = (_Float16)__int_as_float(pooled[i]);
  }
  __syncthreads();

  // ---- fusion: tanh(fus_w @ [h_t; pooled] + b); wave wv owns n-tiles 2wv,2wv+1
  {
    half8 bfF[2][5];
    #pragma unroll
    for (int nt2=0;nt2<2;++nt2)
      #pragma unroll
      for (int kc=0;kc<5;++kc)
        bfF[nt2][kc] = ld8(fus_wf + ((wv*2+nt2)*16+cb)*164 + kc*32 + q*8);
    const float fb0 = fus_b[(wv*2)*16+cb];
    const float fb1 = fus_b[(wv*2+1)*16+cb];
    floatx4 C0 = {0.f,0.f,0.f,0.f}, C1 = {0.f,0.f,0.f,0.f};
    #pragma unroll
    for (int kc=0;kc<5;++kc){
      half8 a = ld8(A16 + cb*164 + kc*32 + q*8);
      C0 = MFMA16(a, bfF[0][kc], C0);
      C1 = MFMA16(a, bfF[1][kc], C1);
    }
    #pragma unroll
    for (int r=0;r<4;++r){
      const long row = base + q*4 + r;
      fused[row*128 + (wv*2)*16+cb]   = fast_tanh(C0[r]+fb0);
      fused[row*128 + (wv*2+1)*16+cb] = fast_tanh(C1[r]+fb1);
    }
  }
}

// ---------------------------------------------------------------------------
// Decoder: 25 autoregressive steps (unchanged from R0 passing version).
// ---------------------------------------------------------------------------
__global__ __launch_bounds__(512, 2) void dec_mfma(
    const float* __restrict__ fused,
    const float* __restrict__ w_ih, const float* __restrict__ w_hh,
    const float* __restrict__ b_ih, const float* __restrict__ b_hh,
    const float* __restrict__ out_w, const float* __restrict__ out_b,
    float* __restrict__ out)
{
  __shared__ _Float16 h_lds[32][136];
  __shared__ float ow_lds[2][128];
  __shared__ float pred_lds[32][2];

  const int tid  = threadIdx.x;
  const int wv   = tid >> 6;
  const int lane = tid & 63;
  const int q    = lane >> 4;
  const int cb   = lane & 15;
  const long base = (long)blockIdx.x * 32;

  for (int i=tid;i<256;i+=512) ow_lds[i>>7][i&127] = out_w[i];
  for (int i=tid;i<4096;i+=512) h_lds[i>>7][i&127] = (_Float16)fused[base*128 + i];
  if (tid<64) pred_lds[tid>>1][tid&1] = 0.f;

  half8 bfrag[4][4];
  int col[4];
  float bias_g[4];
  for (int g=0; g<4; ++g){
    col[g] = g*128 + wv*16 + cb;
    bias_g[g] = b_ih[col[g]] + b_hh[col[g]];
    for (int kc=0; kc<4; ++kc){
      const float* src = w_hh + (long)col[g]*128 + kc*32 + q*8;
      half8 f;
      #pragma unroll
      for (int j=0;j<8;++j) f[j] = (_Float16)src[j];
      bfrag[g][kc] = f;
    }
  }
  float wi0[4], wi1[4];
  for (int g=0; g<4; ++g){ wi0[g] = w_ih[col[g]*2+0]; wi1[g] = w_ih[col[g]*2+1]; }
  float ob0 = out_b[0], ob1 = out_b[1];
  __syncthreads();

  float c_reg[8] = {0,0,0,0,0,0,0,0};
  float h_new[8];

  for (int t=0; t<25; ++t){
    floatx4 acc[4][2];
    #pragma unroll
    for (int mt=0; mt<2; ++mt)
      #pragma unroll
      for (int r=0; r<4; ++r){
        int row = mt*16 + q*4 + r;
        float p0 = pred_lds[row][0], p1 = pred_lds[row][1];
        #pragma unroll
        for (int g=0; g<4; ++g)
          acc[g][mt][r] = bias_g[g] + wi0[g]*p0 + wi1[g]*p1;
      }
    #pragma unroll
    for (int kc=0; kc<4; ++kc){
      half8 a0 = *(const half8*)&h_lds[cb][kc*32 + q*8];
      half8 a1 = *(const half8*)&h_lds[16+cb][kc*32 + q*8];
      #pragma unroll
      for (int g=0; g<4; ++g){
        acc[g][0] = MFMA16(a0, bfrag[g][kc], acc[g][0]);
        acc[g][1] = MFMA16(a1, bfrag[g][kc], acc[g][1]);
      }
    }
    #pragma unroll
    for (int mt=0; mt<2; ++mt)
      #pragma unroll
      for (int r=0; r<4; ++r){
        int idx = mt*4+r;
        float ig = fast_sig(acc[0][mt][r]);
        float fg = fast_sig(acc[1][mt][r]);
        float gg = fast_tanh(acc[2][mt][r]);
        float og = fast_sig(acc[3][mt][r]);
        float c  = fg*c_reg[idx] + ig*gg;
        c_reg[idx] = c;
        h_new[idx] = og*fast_tanh(c);
      }
    __syncthreads();
    {
      int hcol = wv*16 + cb;
      #pragma unroll
      for (int mt=0; mt<2; ++mt)
        #pragma unroll
        for (int r=0; r<4; ++r)
          h_lds[mt*16 + q*4 + r][hcol] = (_Float16)h_new[mt*4+r];
    }
    __syncthreads();
    {
      int pair = tid>>3, part = tid&7;
      int m = pair>>1, oc = pair&1;
      const float* owp = ow_lds[oc];
      float v = 0.f;
      #pragma unroll
      for (int k=part*16; k<part*16+16; ++k) v += owp[k]*(float)h_lds[m][k];
      v += __shfl_down(v, 4, 8);
      v += __shfl_down(v, 2, 8);
      v += __shfl_down(v, 1, 8);
      if (part==0){
        v += (oc ? ob1 : ob0);
        pred_lds[m][oc] = v;
        out[(base+m)*50 + t*2 + oc] = v;
      }
    }
    __syncthreads();
  }
}

// ---------------------------------------------------------------------------
extern "C" void kernel_launch(void* const* d_in, const int* in_sizes, int n_in,
                              void* d_out, int out_size, void* d_ws, size_t ws_size,
                              hipStream_t stream)
{
  (void)in_sizes; (void)n_in; (void)out_size; (void)ws_size;
  const float* target   = (const float*)d_in[0];
  const float* neigh    = (const float*)d_in[1];
  const float* enc_w_ih = (const float*)d_in[4];
  const float* enc_w_hh = (const float*)d_in[5];
  const float* enc_b_ih = (const float*)d_in[6];
  const float* enc_b_hh = (const float*)d_in[7];
  const float* nb_w_ih  = (const float*)d_in[8];
  const float* nb_w_hh  = (const float*)d_in[9];
  const float* nb_b_ih  = (const float*)d_in[10];
  const float* nb_b_hh  = (const float*)d_in[11];
  const float* w1       = (const float*)d_in[12];
  const float* b1       = (const float*)d_in[13];
  const float* w2       = (const float*)d_in[14];
  const float* b2       = (const float*)d_in[15];
  const float* fus_w    = (const float*)d_in[16];
  const float* fus_b    = (const float*)d_in[17];
  const float* dec_w_ih = (const float*)d_in[18];
  const float* dec_w_hh = (const float*)d_in[19];
  const float* dec_b_ih = (const float*)d_in[20];
  const float* dec_b_hh = (const float*)d_in[21];
  const float* out_w    = (const float*)d_in[22];
  const float* out_b    = (const float*)d_in[23];

  char* ws = (char*)d_ws;
  _Float16* h_nb16  = (_Float16*)ws;                       // 16 MB
  _Float16* h_enc16 = (_Float16*)(ws + (16u<<20));         // 2 MB
  float*    fusedp  = (float*)(ws + (18u<<20));            // 4 MB
  char* aux = ws + (22u<<20);
  _Float16* w1f    = (_Float16*)aux;                       // 152,064 B
  _Float16* w2f    = (_Float16*)(aux + 152064);            // 39,168 B
  _Float16* fus_wf = (_Float16*)(aux + 152064 + 39168);    // 41,984 B
  float*    v2bg   = (float*)(aux + 233216);               // 8,192 B
  float*    bgmaxp = (float*)(aux + 241408);               // 128 B

  prep_kernel<<<64, 256, 0, stream>>>(w1, b1, w2, b2, fus_w, w1f, w2f, fus_wf, v2bg, bgmaxp);
  lstm_all<<<2304, 512, 0, stream>>>(target, neigh,
                                     enc_w_ih, enc_w_hh, enc_b_ih, enc_b_hh,
                                     nb_w_ih, nb_w_hh, nb_b_ih, nb_b_hh,
                                     h_enc16, h_nb16);
  social_fuse<<<512, 256, 0, stream>>>(h_enc16, h_nb16, w1f, w2f, fus_wf,
                                       b1, v2bg, bgmaxp, fus_b, fusedp);
  dec_mfma<<<256, 512, 0, stream>>>(fusedp, dec_w_ih, dec_w_hh, dec_b_ih, dec_b_hh,
                                    out_w, out_b, (float*)d_out);
}

// Round 3
// 962.610 us; speedup vs baseline: 2.0114x; 1.0799x over previous
//
#include <hip/hip_runtime.h>

typedef _Float16 half8  __attribute__((ext_vector_type(8)));
typedef _Float16 half4v __attribute__((ext_vector_type(4)));
typedef float  floatx4  __attribute__((ext_vector_type(4)));

#define MFMA16(A,B,C) __builtin_amdgcn_mfma_f32_16x16x32_f16((A),(B),(C),0,0,0)

__device__ __forceinline__ float fast_sig(float x){
  return 1.0f/(1.0f + __builtin_amdgcn_exp2f(-1.4426950408889634f*x));
}
__device__ __forceinline__ float fast_tanh(float x){
  return 1.0f - 2.0f/(1.0f + __builtin_amdgcn_exp2f(2.8853900817779268f*x));
}
// 8B-aligned f16x8 load (2x b64) — for LDS strides that are 8B- but not 16B-multiples
__device__ __forceinline__ half8 ld8(const _Float16* p){
  half4v a = *(const half4v*)p;
  half4v b = *(const half4v*)(p+4);
  return __builtin_shufflevector(a,b,0,1,2,3,4,5,6,7);
}

// grid geometry tables (compile-time foldable)
static __device__ constexpr int DY[27] = {0,0,0,0,0,0,0,0, 1,1,1,1,1,1,1,1, 2,2, 3,3,3,4,4,4,5,5,5};
static __device__ constexpr int DX[27] = {0,1,2,3,4,5,6,7, 0,1,2,3,4,5,6,7, 0,1, 3,4,5,3,4,5,3,4,5};
static __device__ constexpr int PY[9]  = {0,0,0,0,0,0,0,1,4};
static __device__ constexpr int PX[9]  = {1,2,3,4,5,6,7,0,4};
static __device__ constexpr int OY[46] = {0,0,0,0,0,0,0,0, 1,1,1,1,1,1,1,1, 2,2,2,2,2,2,2,2,
                                          3,3,3,3,3,3,3, 4,4,4,4,4, 5,5,5,5,5, 6,6,6,6,6};
static __device__ constexpr int OX[46] = {0,1,2,3,4,5,6,7, 0,1,2,3,4,5,6,7, 0,1,2,3,4,5,6,7,
                                          0,1,2,3,4,5,6, 2,3,4,5,6, 2,3,4,5,6, 2,3,4,5,6};
__device__ constexpr int d1idx(int iy,int ix){
  return (iy<0||iy>7||ix<0||ix>7) ? -1 :
         (iy<=1) ? iy*8+ix :
         (iy==2 && ix<=1) ? 16+ix :
         (iy>=3 && iy<=5 && ix>=3 && ix<=5) ? 18+(iy-3)*3+(ix-3) : -1;
}

// ---------------------------------------------------------------------------
// Combined encoder: blocks [0,256) = target LSTM, [256,2304) = neighbor LSTM.
// One block = 32 sequences, 8 waves. gx via K-padded MFMA (K 7->32, only q==0
// lanes carry data); h double-buffered in LDS -> 1 barrier/step.
// ---------------------------------------------------------------------------
__global__ __launch_bounds__(512, 2) void lstm_all(
    const float* __restrict__ target, const float* __restrict__ neigh,
    const float* __restrict__ e_wih, const float* __restrict__ e_whh,
    const float* __restrict__ e_bih, const float* __restrict__ e_bhh,
    const float* __restrict__ n_wih, const float* __restrict__ n_whh,
    const float* __restrict__ n_bih, const float* __restrict__ n_bhh,
    _Float16* __restrict__ h_enc16, _Float16* __restrict__ h_nb16)
{
  __shared__ _Float16 h_lds[2][32][136];   // double-buffered h
  __shared__ _Float16 xf16[32][168];       // [seq][t*8 + f], f=7 is zero pad

  const int tid  = threadIdx.x;
  const int wv   = tid >> 6;
  const int lane = tid & 63;
  const int q    = lane >> 4;
  const int cb   = lane & 15;

  const bool enc = (blockIdx.x < 256);
  const float* x   = enc ? target : neigh;
  const float* wih = enc ? e_wih : n_wih;
  const float* whh = enc ? e_whh : n_whh;
  const float* bih = enc ? e_bih : n_bih;
  const float* bhh = enc ? e_bhh : n_bhh;
  _Float16* hout   = enc ? h_enc16 : h_nb16;
  const long base  = enc ? (long)blockIdx.x*32 : (long)(blockIdx.x-256)*32;

  // stage x as padded f16: one pass, each element written by exactly one thread
  for (int i = tid; i < 32*160; i += 512){
    int seq = i/160, rem = i%160, t = rem>>3, f = rem&7;
    xf16[seq][t*8+f] = (f<7) ? (_Float16)x[base*140 + seq*140 + t*7 + f] : (_Float16)0.f;
  }
  for (int i = tid; i < 32*136; i += 512) ((_Float16*)h_lds[0])[i] = (_Float16)0.f;

  half8 bfrag[4][4];   // w_hh B-frags
  half8 bwih[4];       // w_ih B-frags (K-padded: q==0, j<7 live)
  int col[4];
  float bias_g[4];
  for (int g=0; g<4; ++g){
    col[g] = g*128 + wv*16 + cb;
    bias_g[g] = bih[col[g]] + bhh[col[g]];
    for (int kc=0; kc<4; ++kc){
      const float* src = whh + (long)col[g]*128 + kc*32 + q*8;
      half8 f;
      #pragma unroll
      for (int j=0;j<8;++j) f[j] = (_Float16)src[j];
      bfrag[g][kc] = f;
    }
    half8 f = {0,0,0,0,0,0,0,0};
    if (q == 0){
      #pragma unroll
      for (int j=0;j<7;++j) f[j] = (_Float16)wih[col[g]*7+j];
    }
    bwih[g] = f;
  }
  __syncthreads();

  float c_reg[8] = {0,0,0,0,0,0,0,0};
  float h_new[8] = {0,0,0,0,0,0,0,0};

  for (int t=0; t<20; ++t){
    const _Float16 (*hr)[136] = h_lds[t&1];
    _Float16 (*hw)[136]       = h_lds[(t+1)&1];

    floatx4 acc[4][2];
    #pragma unroll
    for (int g=0; g<4; ++g){
      float bv = bias_g[g];
      acc[g][0] = (floatx4){bv,bv,bv,bv};
      acc[g][1] = (floatx4){bv,bv,bv,bv};
    }
    // input projection via K-padded MFMA
    {
      half8 ax0 = {0,0,0,0,0,0,0,0}, ax1 = {0,0,0,0,0,0,0,0};
      if (q == 0){
        ax0 = *(const half8*)&xf16[cb][t*8];
        ax1 = *(const half8*)&xf16[16+cb][t*8];
      }
      #pragma unroll
      for (int g=0; g<4; ++g){
        acc[g][0] = MFMA16(ax0, bwih[g], acc[g][0]);
        acc[g][1] = MFMA16(ax1, bwih[g], acc[g][1]);
      }
    }
    // hidden projection
    #pragma unroll
    for (int kc=0; kc<4; ++kc){
      half8 a0 = *(const half8*)&hr[cb][kc*32 + q*8];
      half8 a1 = *(const half8*)&hr[16+cb][kc*32 + q*8];
      #pragma unroll
      for (int g=0; g<4; ++g){
        acc[g][0] = MFMA16(a0, bfrag[g][kc], acc[g][0]);
        acc[g][1] = MFMA16(a1, bfrag[g][kc], acc[g][1]);
      }
    }
    #pragma unroll
    for (int mt=0; mt<2; ++mt)
      #pragma unroll
      for (int r=0; r<4; ++r){
        int idx = mt*4+r;
        float ig = fast_sig(acc[0][mt][r]);
        float fg = fast_sig(acc[1][mt][r]);
        float gg = fast_tanh(acc[2][mt][r]);
        float og = fast_sig(acc[3][mt][r]);
        float c  = fg*c_reg[idx] + ig*gg;
        c_reg[idx] = c;
        h_new[idx] = og*fast_tanh(c);
      }
    {
      int hcol = wv*16 + cb;
      #pragma unroll
      for (int mt=0; mt<2; ++mt)
        #pragma unroll
        for (int r=0; r<4; ++r)
          hw[mt*16 + q*4 + r][hcol] = (_Float16)h_new[mt*4+r];
    }
    __syncthreads();   // h(t+1) visible; also orders next step's WAR on hr
  }

  {
    int hcol = wv*16 + cb;
    #pragma unroll
    for (int mt=0; mt<2; ++mt)
      #pragma unroll
      for (int r=0; r<4; ++r)
        hout[(base + mt*16 + q*4 + r)*128 + hcol] = (_Float16)h_new[mt*4+r];
  }
}

// ---------------------------------------------------------------------------
// Prep: weights into MFMA B-fragment-friendly f16 layouts + conv2 background.
// ---------------------------------------------------------------------------
__global__ void prep_kernel(const float* __restrict__ w1, const float* __restrict__ b1,
                            const float* __restrict__ w2, const float* __restrict__ b2,
                            const float* __restrict__ fus_w,
                            _Float16* __restrict__ w1f, _Float16* __restrict__ w2f,
                            _Float16* __restrict__ fus_wf,
                            float* __restrict__ v2bg, float* __restrict__ bgmax)
{
  const int tid = threadIdx.x;
  const int gid = blockIdx.x*256 + tid;
  const int gstride = gridDim.x*256;
  for (int i = gid; i < 9*64*128; i += gstride){
    int s = i>>13, rem = i&8191, c1 = rem>>7, ci = rem&127;
    w1f[s*8448 + c1*132 + ci] = (_Float16)w1[c1*1152 + ci*9 + s];
  }
  for (int i = gid; i < 9*32*64; i += gstride){
    int s = i>>11, rem = i&2047, c2 = rem>>6, ci = rem&63;
    w2f[s*2176 + c2*68 + ci] = (_Float16)w2[c2*576 + ci*9 + s];
  }
  for (int i = gid; i < 128*160; i += gstride){
    int n = i/160, k = i%160;
    fus_wf[n*164 + k] = (_Float16)fus_w[i];
  }
  if (blockIdx.x == 0){
    __shared__ float S[288];
    __shared__ int bgm[32];
    for (int i=tid;i<288;i+=256){
      int c2=i/9, s=i%9;
      float a=0.f;
      for (int ci=0;ci<64;++ci) a += w2[c2*576+ci*9+s]*fmaxf(b1[ci],0.f);
      S[i]=a;
    }
    if (tid<32) bgm[tid]=0;
    __syncthreads();
    for (int i=tid;i<2048;i+=256){
      int cell=i>>5, c2=i&31, y=cell>>3, xx=cell&7;
      float a=b2[c2];
      for (int dy=0;dy<3;++dy){ int iy=y+dy-1; if((unsigned)iy>7u) continue;
        for (int dx=0;dx<3;++dx){ int ix=xx+dx-1; if((unsigned)ix>7u) continue;
          a += S[c2*9+dy*3+dx]; } }
      v2bg[cell*32+c2]=a;
      bool aff = (y<=2) || (y==3 && xx<=6) || (y>=4 && y<=6 && xx>=2 && xx<=6);
      if(!aff) atomicMax(&bgm[c2], __float_as_int(fmaxf(a,0.f)));
    }
    __syncthreads();
    if (tid<32) bgmax[tid]=__int_as_float(bgm[tid]);
  }
}

// ---------------------------------------------------------------------------
// Social pooling + sparse conv stack + maxpool + fusion, MFMA formulation.
// (unchanged from R1 — fell out of the top-5)
// ---------------------------------------------------------------------------
__global__ __launch_bounds__(256, 1) void social_fuse(
    const _Float16* __restrict__ h_enc, const _Float16* __restrict__ h_nb,
    const _Float16* __restrict__ w1f, const _Float16* __restrict__ w2f,
    const _Float16* __restrict__ fus_wf,
    const float* __restrict__ b1, const float* __restrict__ v2bg,
    const float* __restrict__ bgmax, const float* __restrict__ fus_b,
    float* __restrict__ fused)
{
  __shared__ __align__(16) _Float16 vecs[9*16*132];
  __shared__ __align__(16) _Float16 d1[27*16*68];
  __shared__ __align__(16) _Float16 A16[16*164];
  __shared__ int pooled[512];

  const int tid  = threadIdx.x;
  const int wv   = tid >> 6;
  const int lane = tid & 63;
  const int q    = lane >> 4;
  const int cb   = lane & 15;
  const long base = (long)blockIdx.x * 16;

  for (int i=tid; i<9*16*32; i+=256){
    int p = i>>9, rem = i&511, bb = rem>>5, j = rem&31;
    const _Float16* src = (p<8) ? (h_nb + (((base+bb))*8 + p)*128 + j*4)
                                : (h_enc + (base+bb)*128 + j*4);
    *(unsigned long long*)(vecs + p*2112 + bb*132 + j*4) = *(const unsigned long long*)src;
  }
  for (int i=tid; i<512; i+=256){
    int bb=i>>5, j=i&31;
    *(unsigned long long*)(A16 + bb*164 + j*4) =
        *(const unsigned long long*)(h_enc + (base+bb)*128 + j*4);
  }
  for (int i=tid; i<512; i+=256) pooled[i] = __float_as_int(bgmax[i&31]);
  __syncthreads();

  {
    const int c1lane = wv*16 + cb;
    half8 bf1[9][4];
    #pragma unroll
    for (int s=0;s<9;++s)
      #pragma unroll
      for (int kc=0;kc<4;++kc)
        bf1[s][kc] = ld8(w1f + s*8448 + c1lane*132 + kc*32 + q*8);
    const float b1v = b1[c1lane];
    const float bg  = fmaxf(b1v, 0.f);

    #pragma unroll
    for (int ci=0; ci<27; ++ci){
      const int y = DY[ci], x = DX[ci];
      floatx4 C = {0.f,0.f,0.f,0.f};
      #pragma unroll
      for (int p=0;p<9;++p){
        const int dy = PY[p]-y+1, dx = PX[p]-x+1;
        if (dy>=0 && dy<3 && dx>=0 && dx<3){
          const int s = dy*3+dx;
          const _Float16* ap = vecs + p*2112 + cb*132 + q*8;
          #pragma unroll
          for (int kc=0;kc<4;++kc)
            C = MFMA16(ld8(ap + kc*32), bf1[s][kc], C);
        }
      }
      _Float16* dp = d1 + ci*1088 + c1lane;
      #pragma unroll
      for (int r=0;r<4;++r)
        dp[(q*4+r)*68] = (_Float16)(fmaxf(b1v + C[r], 0.f) - bg);
    }
  }
  __syncthreads();

  {
    half8 bf2[9][2][2];
    #pragma unroll
    for (int s=0;s<9;++s)
      #pragma unroll
      for (int nt=0;nt<2;++nt)
        #pragma unroll
        for (int kc=0;kc<2;++kc)
          bf2[s][nt][kc] = ld8(w2f + s*2176 + (nt*16+cb)*68 + kc*32 + q*8);

    float rm0[4] = {0,0,0,0}, rm1[4] = {0,0,0,0};
    #pragma unroll
    for (int oc=0; oc<46; ++oc){
      if ((oc & 3) != wv) continue;
      const int y = OY[oc], x = OX[oc];
      const int cell = y*8+x;
      float v0 = v2bg[cell*32 + cb];
      float v1 = v2bg[cell*32 + 16 + cb];
      floatx4 C0 = {v0,v0,v0,v0}, C1 = {v1,v1,v1,v1};
      #pragma unroll
      for (int dy=0;dy<3;++dy)
        #pragma unroll
        for (int dx=0;dx<3;++dx){
          const int dc = d1idx(y+dy-1, x+dx-1);
          if (dc < 0) continue;
          const int s = dy*3+dx;
          const _Float16* ap = d1 + dc*1088 + cb*68 + q*8;
          #pragma unroll
          for (int kc=0;kc<2;++kc){
            half8 a = ld8(ap + kc*32);
            C0 = MFMA16(a, bf2[s][0][kc], C0);
            C1 = MFMA16(a, bf2[s][1][kc], C1);
          }
        }
      #pragma unroll
      for (int r=0;r<4;++r){
        rm0[r] = fmaxf(rm0[r], fmaxf(C0[r],0.f));
        rm1[r] = fmaxf(rm1[r], fmaxf(C1[r],0.f));
      }
    }
    #pragma unroll
    for (int r=0;r<4;++r){
      atomicMax(&pooled[(q*4+r)*32 + cb],      __float_as_int(rm0[r]));
      atomicMax(&pooled[(q*4+r)*32 + 16 + cb], __float_as_int(rm1[r]));
    }
  }
  __syncthreads();

  for (int i=tid;i<512;i+=256){
    int bb=i>>5, c2=i&31;
    A16[bb*164 + 128 + c2] = (_Float16)__int_as_float(pooled[i]);
  }
  __syncthreads();

  {
    half8 bfF[2][5];
    #pragma unroll
    for (int nt2=0;nt2<2;++nt2)
      #pragma unroll
      for (int kc=0;kc<5;++kc)
        bfF[nt2][kc] = ld8(fus_wf + ((wv*2+nt2)*16+cb)*164 + kc*32 + q*8);
    const float fb0 = fus_b[(wv*2)*16+cb];
    const float fb1 = fus_b[(wv*2+1)*16+cb];
    floatx4 C0 = {0.f,0.f,0.f,0.f}, C1 = {0.f,0.f,0.f,0.f};
    #pragma unroll
    for (int kc=0;kc<5;++kc){
      half8 a = ld8(A16 + cb*164 + kc*32 + q*8);
      C0 = MFMA16(a, bfF[0][kc], C0);
      C1 = MFMA16(a, bfF[1][kc], C1);
    }
    #pragma unroll
    for (int r=0;r<4;++r){
      const long row = base + q*4 + r;
      fused[row*128 + (wv*2)*16+cb]   = fast_tanh(C0[r]+fb0);
      fused[row*128 + (wv*2+1)*16+cb] = fast_tanh(C1[r]+fb1);
    }
  }
}

// ---------------------------------------------------------------------------
// Decoder: 25 autoregressive steps; double-buffered h -> 2 barriers/step.
// ---------------------------------------------------------------------------
__global__ __launch_bounds__(512, 2) void dec_mfma(
    const float* __restrict__ fused,
    const float* __restrict__ w_ih, const float* __restrict__ w_hh,
    const float* __restrict__ b_ih, const float* __restrict__ b_hh,
    const float* __restrict__ out_w, const float* __restrict__ out_b,
    float* __restrict__ out)
{
  __shared__ _Float16 h_lds[2][32][136];
  __shared__ float ow_lds[2][128];
  __shared__ float pred_lds[32][2];

  const int tid  = threadIdx.x;
  const int wv   = tid >> 6;
  const int lane = tid & 63;
  const int q    = lane >> 4;
  const int cb   = lane & 15;
  const long base = (long)blockIdx.x * 32;

  for (int i=tid;i<256;i+=512) ow_lds[i>>7][i&127] = out_w[i];
  for (int i=tid;i<4096;i+=512) h_lds[0][i>>7][i&127] = (_Float16)fused[base*128 + i];
  if (tid<64) pred_lds[tid>>1][tid&1] = 0.f;

  half8 bfrag[4][4];
  int col[4];
  float bias_g[4];
  for (int g=0; g<4; ++g){
    col[g] = g*128 + wv*16 + cb;
    bias_g[g] = b_ih[col[g]] + b_hh[col[g]];
    for (int kc=0; kc<4; ++kc){
      const float* src = w_hh + (long)col[g]*128 + kc*32 + q*8;
      half8 f;
      #pragma unroll
      for (int j=0;j<8;++j) f[j] = (_Float16)src[j];
      bfrag[g][kc] = f;
    }
  }
  float wi0[4], wi1[4];
  for (int g=0; g<4; ++g){ wi0[g] = w_ih[col[g]*2+0]; wi1[g] = w_ih[col[g]*2+1]; }
  float ob0 = out_b[0], ob1 = out_b[1];
  __syncthreads();

  float c_reg[8] = {0,0,0,0,0,0,0,0};
  float h_new[8];

  for (int t=0; t<25; ++t){
    const _Float16 (*hr)[136] = h_lds[t&1];
    _Float16 (*hw)[136]       = h_lds[(t+1)&1];

    floatx4 acc[4][2];
    #pragma unroll
    for (int mt=0; mt<2; ++mt)
      #pragma unroll
      for (int r=0; r<4; ++r){
        int row = mt*16 + q*4 + r;
        float p0 = pred_lds[row][0], p1 = pred_lds[row][1];
        #pragma unroll
        for (int g=0; g<4; ++g)
          acc[g][mt][r] = bias_g[g] + wi0[g]*p0 + wi1[g]*p1;
      }
    #pragma unroll
    for (int kc=0; kc<4; ++kc){
      half8 a0 = *(const half8*)&hr[cb][kc*32 + q*8];
      half8 a1 = *(const half8*)&hr[16+cb][kc*32 + q*8];
      #pragma unroll
      for (int g=0; g<4; ++g){
        acc[g][0] = MFMA16(a0, bfrag[g][kc], acc[g][0]);
        acc[g][1] = MFMA16(a1, bfrag[g][kc], acc[g][1]);
      }
    }
    #pragma unroll
    for (int mt=0; mt<2; ++mt)
      #pragma unroll
      for (int r=0; r<4; ++r){
        int idx = mt*4+r;
        float ig = fast_sig(acc[0][mt][r]);
        float fg = fast_sig(acc[1][mt][r]);
        float gg = fast_tanh(acc[2][mt][r]);
        float og = fast_sig(acc[3][mt][r]);
        float c  = fg*c_reg[idx] + ig*gg;
        c_reg[idx] = c;
        h_new[idx] = og*fast_tanh(c);
      }
    {
      int hcol = wv*16 + cb;
      #pragma unroll
      for (int mt=0; mt<2; ++mt)
        #pragma unroll
        for (int r=0; r<4; ++r)
          hw[mt*16 + q*4 + r][hcol] = (_Float16)h_new[mt*4+r];
    }
    __syncthreads();    // h(t+1) visible for projection + next step
    {
      int pair = tid>>3, part = tid&7;
      int m = pair>>1, oc = pair&1;
      const float* owp = ow_lds[oc];
      float v = 0.f;
      #pragma unroll
      for (int k=part*16; k<part*16+16; ++k) v += owp[k]*(float)hw[m][k];
      v += __shfl_down(v, 4, 8);
      v += __shfl_down(v, 2, 8);
      v += __shfl_down(v, 1, 8);
      if (part==0){
        v += (oc ? ob1 : ob0);
        pred_lds[m][oc] = v;
        out[(base+m)*50 + t*2 + oc] = v;
      }
    }
    __syncthreads();    // pred(t) visible for next step's acc init
  }
}

// ---------------------------------------------------------------------------
extern "C" void kernel_launch(void* const* d_in, const int* in_sizes, int n_in,
                              void* d_out, int out_size, void* d_ws, size_t ws_size,
                              hipStream_t stream)
{
  (void)in_sizes; (void)n_in; (void)out_size; (void)ws_size;
  const float* target   = (const float*)d_in[0];
  const float* neigh    = (const float*)d_in[1];
  const float* enc_w_ih = (const float*)d_in[4];
  const float* enc_w_hh = (const float*)d_in[5];
  const float* enc_b_ih = (const float*)d_in[6];
  const float* enc_b_hh = (const float*)d_in[7];
  const float* nb_w_ih  = (const float*)d_in[8];
  const float* nb_w_hh  = (const float*)d_in[9];
  const float* nb_b_ih  = (const float*)d_in[10];
  const float* nb_b_hh  = (const float*)d_in[11];
  const float* w1       = (const float*)d_in[12];
  const float* b1       = (const float*)d_in[13];
  const float* w2       = (const float*)d_in[14];
  const float* b2       = (const float*)d_in[15];
  const float* fus_w    = (const float*)d_in[16];
  const float* fus_b    = (const float*)d_in[17];
  const float* dec_w_ih = (const float*)d_in[18];
  const float* dec_w_hh = (const float*)d_in[19];
  const float* dec_b_ih = (const float*)d_in[20];
  const float* dec_b_hh = (const float*)d_in[21];
  const float* out_w    = (const float*)d_in[22];
  const float* out_b    = (const float*)d_in[23];

  char* ws = (char*)d_ws;
  _Float16* h_nb16  = (_Float16*)ws;                       // 16 MB
  _Float16* h_enc16 = (_Float16*)(ws + (16u<<20));         // 2 MB
  float*    fusedp  = (float*)(ws + (18u<<20));            // 4 MB
  char* aux = ws + (22u<<20);
  _Float16* w1f    = (_Float16*)aux;                       // 152,064 B
  _Float16* w2f    = (_Float16*)(aux + 152064);            // 39,168 B
  _Float16* fus_wf = (_Float16*)(aux + 152064 + 39168);    // 41,984 B
  float*    v2bg   = (float*)(aux + 233216);               // 8,192 B
  float*    bgmaxp = (float*)(aux + 241408);               // 128 B

  prep_kernel<<<64, 256, 0, stream>>>(w1, b1, w2, b2, fus_w, w1f, w2f, fus_wf, v2bg, bgmaxp);
  lstm_all<<<2304, 512, 0, stream>>>(target, neigh,
                                     enc_w_ih, enc_w_hh, enc_b_ih, enc_b_hh,
                                     nb_w_ih, nb_w_hh, nb_b_ih, nb_b_hh,
                                     h_enc16, h_nb16);
  social_fuse<<<512, 256, 0, stream>>>(h_enc16, h_nb16, w1f, w2f, fus_wf,
                                       b1, v2bg, bgmaxp, fus_b, fusedp);
  dec_mfma<<<256, 512, 0, stream>>>(fusedp, dec_w_ih, dec_w_hh, dec_b_ih, dec_b_hh,
                                    out_w, out_b, (float*)d_out);
}

// Round 6
// 595.107 us; speedup vs baseline: 3.2535x; 1.6175x over previous
//
#include <hip/hip_runtime.h>

typedef _Float16 half8  __attribute__((ext_vector_type(8)));
typedef _Float16 half4v __attribute__((ext_vector_type(4)));
typedef float  floatx4  __attribute__((ext_vector_type(4)));

#define MFMA16(A,B,C) __builtin_amdgcn_mfma_f32_16x16x32_f16((A),(B),(C),0,0,0)

#define L2E  1.4426950408889634f
#define L2E2 2.8853900817779268f

// prescaled-domain activations: y = L2E*x (sig) / 2*L2E*x (tanh). One exp2 +
// one rcp each (no fast-math in harness: plain / = full IEEE divide sequence).
__device__ __forceinline__ float sig_pre(float y){
  return __builtin_amdgcn_rcpf(1.0f + __builtin_amdgcn_exp2f(-y));
}
__device__ __forceinline__ float tanh_pre(float y){
  return 1.0f - 2.0f*__builtin_amdgcn_rcpf(1.0f + __builtin_amdgcn_exp2f(y));
}
__device__ __forceinline__ float tanh_raw(float c){
  return 1.0f - 2.0f*__builtin_amdgcn_rcpf(1.0f + __builtin_amdgcn_exp2f(L2E2*c));
}
// 8B-aligned f16x8 load (2x b64) — for LDS strides that are 8B- but not 16B-multiples
__device__ __forceinline__ half8 ld8(const _Float16* p){
  half4v a = *(const half4v*)p;
  half4v b = *(const half4v*)(p+4);
  return __builtin_shufflevector(a,b,0,1,2,3,4,5,6,7);
}

// grid geometry tables (compile-time foldable)
static __device__ constexpr int DY[27] = {0,0,0,0,0,0,0,0, 1,1,1,1,1,1,1,1, 2,2, 3,3,3,4,4,4,5,5,5};
static __device__ constexpr int DX[27] = {0,1,2,3,4,5,6,7, 0,1,2,3,4,5,6,7, 0,1, 3,4,5,3,4,5,3,4,5};
static __device__ constexpr int PY[9]  = {0,0,0,0,0,0,0,1,4};
static __device__ constexpr int PX[9]  = {1,2,3,4,5,6,7,0,4};
static __device__ constexpr int OY[46] = {0,0,0,0,0,0,0,0, 1,1,1,1,1,1,1,1, 2,2,2,2,2,2,2,2,
                                          3,3,3,3,3,3,3, 4,4,4,4,4, 5,5,5,5,5, 6,6,6,6,6};
static __device__ constexpr int OX[46] = {0,1,2,3,4,5,6,7, 0,1,2,3,4,5,6,7, 0,1,2,3,4,5,6,7,
                                          0,1,2,3,4,5,6, 2,3,4,5,6, 2,3,4,5,6, 2,3,4,5,6};
__device__ constexpr int d1idx(int iy,int ix){
  return (iy<0||iy>7||ix<0||ix>7) ? -1 :
         (iy<=1) ? iy*8+ix :
         (iy==2 && ix<=1) ? 16+ix :
         (iy>=3 && iy<=5 && ix>=3 && ix<=5) ? 18+(iy-3)*3+(ix-3) : -1;
}

// ---------------------------------------------------------------------------
// Combined encoder: blocks [0,512) = target LSTM, [512,4608) = neighbor LSTM.
// One block = 16 sequences (M=16), 8 waves; wave owns 16 hidden cols x 4 gates.
// Merged-K: h row = [h(128) | x(t)(7) | 1.0 | zeros], K=160 in 5 chunks; the
// 5th B-chunk carries w_ih and bias (prescaled by log2e; g-gate by 2*log2e).
// NOTE: a[4] reads h-row cols 128..160 across quadrants; cols 136..168 must be
// ZERO in BOTH buffers (NaN*0=NaN in MFMA) — zero-init covers the full array,
// and per-step writes never touch cols >=136.
// ---------------------------------------------------------------------------
__global__ __launch_bounds__(512, 4) void lstm_all(
    const float* __restrict__ target, const float* __restrict__ neigh,
    const float* __restrict__ e_wih, const float* __restrict__ e_whh,
    const float* __restrict__ e_bih, const float* __restrict__ e_bhh,
    const float* __restrict__ n_wih, const float* __restrict__ n_whh,
    const float* __restrict__ n_bih, const float* __restrict__ n_bhh,
    _Float16* __restrict__ h_enc16, _Float16* __restrict__ h_nb16)
{
  __shared__ _Float16 h_lds[2][16][168];   // row: 128 h + 8 x-tail + 32 zero
  __shared__ _Float16 xf16[16][168];       // [seq][t*8+f]; f==7 slot = 1.0 bias carrier

  const int tid  = threadIdx.x;
  const int wv   = tid >> 6;
  const int lane = tid & 63;
  const int q    = lane >> 4;
  const int cb   = lane & 15;

  const bool enc = (blockIdx.x < 512);
  const float* x   = enc ? target : neigh;
  const float* wih = enc ? e_wih : n_wih;
  const float* whh = enc ? e_whh : n_whh;
  const float* bih = enc ? e_bih : n_bih;
  const float* bhh = enc ? e_bhh : n_bhh;
  _Float16* hout   = enc ? h_enc16 : h_nb16;
  const long base  = enc ? (long)blockIdx.x*16 : (long)(blockIdx.x-512)*16;

  for (int i = tid; i < 16*168; i += 512){
    int seq = i/168, rem = i%168, t = rem>>3, f = rem&7;
    float v = 0.f;
    if (t < 20) v = (f < 7) ? x[base*140 + seq*140 + t*7 + f] : 1.0f;
    xf16[seq][rem] = (_Float16)v;
  }
  for (int i = tid; i < 2*16*168; i += 512) ((_Float16*)h_lds)[i] = (_Float16)0.f;

  // B-frags: kc 0..3 = w_hh, kc 4 = [w_ih | bias | 0...]; gate-prescaled.
  half8 bfrag[4][5];
  #pragma unroll
  for (int g=0; g<4; ++g){
    const float sc = (g==2) ? L2E2 : L2E;
    const int col = g*128 + wv*16 + cb;
    #pragma unroll
    for (int kc=0; kc<4; ++kc){
      const float* src = whh + (long)col*128 + kc*32 + q*8;
      half8 f;
      #pragma unroll
      for (int j=0;j<8;++j) f[j] = (_Float16)(src[j]*sc);
      bfrag[g][kc] = f;
    }
    half8 f = {0,0,0,0,0,0,0,0};
    if (q == 0){
      #pragma unroll
      for (int j=0;j<7;++j) f[j] = (_Float16)(wih[col*7+j]*sc);
      f[7] = (_Float16)((bih[col]+bhh[col])*sc);
    }
    bfrag[g][4] = f;
  }
  __syncthreads();
  if (tid < 16)   // x(0) + bias carrier into h(0) tail
    *(half8*)&h_lds[0][tid][128] = *(const half8*)&xf16[tid][0];
  __syncthreads();

  const int hcol = wv*16 + cb;
  float c_reg[4] = {0,0,0,0};
  float h_new[4] = {0,0,0,0};
  const floatx4 ZERO4 = {0.f,0.f,0.f,0.f};

  for (int t=0; t<20; ++t){
    const _Float16 (*hr)[168] = h_lds[t&1];
    _Float16 (*hw)[168]       = h_lds[(t+1)&1];

    half8 a[5];
    #pragma unroll
    for (int kc=0; kc<5; ++kc) a[kc] = *(const half8*)&hr[cb][kc*32 + q*8];

    floatx4 acc[4];
    #pragma unroll
    for (int g=0; g<4; ++g){
      acc[g] = MFMA16(a[4], bfrag[g][4], ZERO4);
      #pragma unroll
      for (int kc=0; kc<4; ++kc)
        acc[g] = MFMA16(a[kc], bfrag[g][kc], acc[g]);
    }
    #pragma unroll
    for (int r=0; r<4; ++r){
      float ig = sig_pre(acc[0][r]);
      float fg = sig_pre(acc[1][r]);
      float gg = tanh_pre(acc[2][r]);
      float og = sig_pre(acc[3][r]);
      float c  = fg*c_reg[r] + ig*gg;
      c_reg[r] = c;
      h_new[r] = og*tanh_raw(c);
    }
    #pragma unroll
    for (int r=0; r<4; ++r) hw[q*4 + r][hcol] = (_Float16)h_new[r];
    if (tid < 16)   // x(t+1) tail into the buffer read next step
      *(half8*)&hw[tid][128] = *(const half8*)&xf16[tid][(t+1)*8];
    __syncthreads();
  }

  #pragma unroll
  for (int r=0; r<4; ++r)
    hout[(base + q*4 + r)*128 + hcol] = (_Float16)h_new[r];
}

// ---------------------------------------------------------------------------
// Prep: weights into MFMA B-fragment-friendly f16 layouts + conv2 background.
// ---------------------------------------------------------------------------
__global__ void prep_kernel(const float* __restrict__ w1, const float* __restrict__ b1,
                            const float* __restrict__ w2, const float* __restrict__ b2,
                            const float* __restrict__ fus_w,
                            _Float16* __restrict__ w1f, _Float16* __restrict__ w2f,
                            _Float16* __restrict__ fus_wf,
                            float* __restrict__ v2bg, float* __restrict__ bgmax)
{
  const int tid = threadIdx.x;
  const int gid = blockIdx.x*256 + tid;
  const int gstride = gridDim.x*256;
  for (int i = gid; i < 9*64*128; i += gstride){
    int s = i>>13, rem = i&8191, c1 = rem>>7, ci = rem&127;
    w1f[s*8448 + c1*132 + ci] = (_Float16)w1[c1*1152 + ci*9 + s];
  }
  for (int i = gid; i < 9*32*64; i += gstride){
    int s = i>>11, rem = i&2047, c2 = rem>>6, ci = rem&63;
    w2f[s*2176 + c2*68 + ci] = (_Float16)w2[c2*576 + ci*9 + s];
  }
  for (int i = gid; i < 128*160; i += gstride){
    int n = i/160, k = i%160;
    fus_wf[n*164 + k] = (_Float16)fus_w[i];
  }
  if (blockIdx.x == 0){
    __shared__ float S[288];
    __shared__ int bgm[32];
    for (int i=tid;i<288;i+=256){
      int c2=i/9, s=i%9;
      float a=0.f;
      for (int ci=0;ci<64;++ci) a += w2[c2*576+ci*9+s]*fmaxf(b1[ci],0.f);
      S[i]=a;
    }
    if (tid<32) bgm[tid]=0;
    __syncthreads();
    for (int i=tid;i<2048;i+=256){
      int cell=i>>5, c2=i&31, y=cell>>3, xx=cell&7;
      float a=b2[c2];
      for (int dy=0;dy<3;++dy){ int iy=y+dy-1; if((unsigned)iy>7u) continue;
        for (int dx=0;dx<3;++dx){ int ix=xx+dx-1; if((unsigned)ix>7u) continue;
          a += S[c2*9+dy*3+dx]; } }
      v2bg[cell*32+c2]=a;
      bool aff = (y<=2) || (y==3 && xx<=6) || (y>=4 && y<=6 && xx>=2 && xx<=6);
      if(!aff) atomicMax(&bgm[c2], __float_as_int(fmaxf(a,0.f)));
    }
    __syncthreads();
    if (tid<32) bgmax[tid]=__int_as_float(bgm[tid]);
  }
}

// ---------------------------------------------------------------------------
// Social pooling + sparse conv stack + maxpool + fusion, MFMA formulation.
// ---------------------------------------------------------------------------
__global__ __launch_bounds__(256, 1) void social_fuse(
    const _Float16* __restrict__ h_enc, const _Float16* __restrict__ h_nb,
    const _Float16* __restrict__ w1f, const _Float16* __restrict__ w2f,
    const _Float16* __restrict__ fus_wf,
    const float* __restrict__ b1, const float* __restrict__ v2bg,
    const float* __restrict__ bgmax, const float* __restrict__ fus_b,
    float* __restrict__ fused)
{
  __shared__ __align__(16) _Float16 vecs[9*16*132];
  __shared__ __align__(16) _Float16 d1[27*16*68];
  __shared__ __align__(16) _Float16 A16[16*164];
  __shared__ int pooled[512];

  const int tid  = threadIdx.x;
  const int wv   = tid >> 6;
  const int lane = tid & 63;
  const int q    = lane >> 4;
  const int cb   = lane & 15;
  const long base = (long)blockIdx.x * 16;

  for (int i=tid; i<9*16*32; i+=256){
    int p = i>>9, rem = i&511, bb = rem>>5, j = rem&31;
    const _Float16* src = (p<8) ? (h_nb + (((base+bb))*8 + p)*128 + j*4)
                                : (h_enc + (base+bb)*128 + j*4);
    *(unsigned long long*)(vecs + p*2112 + bb*132 + j*4) = *(const unsigned long long*)src;
  }
  for (int i=tid; i<512; i+=256){
    int bb=i>>5, j=i&31;
    *(unsigned long long*)(A16 + bb*164 + j*4) =
        *(const unsigned long long*)(h_enc + (base+bb)*128 + j*4);
  }
  for (int i=tid; i<512; i+=256) pooled[i] = __float_as_int(bgmax[i&31]);
  __syncthreads();

  {
    const int c1lane = wv*16 + cb;
    half8 bf1[9][4];
    #pragma unroll
    for (int s=0;s<9;++s)
      #pragma unroll
      for (int kc=0;kc<4;++kc)
        bf1[s][kc] = ld8(w1f + s*8448 + c1lane*132 + kc*32 + q*8);
    const float b1v = b1[c1lane];
    const float bg  = fmaxf(b1v, 0.f);

    #pragma unroll
    for (int ci=0; ci<27; ++ci){
      const int y = DY[ci], x = DX[ci];
      floatx4 C = {0.f,0.f,0.f,0.f};
      #pragma unroll
      for (int p=0;p<9;++p){
        const int dy = PY[p]-y+1, dx = PX[p]-x+1;
        if (dy>=0 && dy<3 && dx>=0 && dx<3){
          const int s = dy*3+dx;
          const _Float16* ap = vecs + p*2112 + cb*132 + q*8;
          #pragma unroll
          for (int kc=0;kc<4;++kc)
            C = MFMA16(ld8(ap + kc*32), bf1[s][kc], C);
        }
      }
      _Float16* dp = d1 + ci*1088 + c1lane;
      #pragma unroll
      for (int r=0;r<4;++r)
        dp[(q*4+r)*68] = (_Float16)(fmaxf(b1v + C[r], 0.f) - bg);
    }
  }
  __syncthreads();

  {
    half8 bf2[9][2][2];
    #pragma unroll
    for (int s=0;s<9;++s)
      #pragma unroll
      for (int nt=0;nt<2;++nt)
        #pragma unroll
        for (int kc=0;kc<2;++kc)
          bf2[s][nt][kc] = ld8(w2f + s*2176 + (nt*16+cb)*68 + kc*32 + q*8);

    float rm0[4] = {0,0,0,0}, rm1[4] = {0,0,0,0};
    #pragma unroll
    for (int oc=0; oc<46; ++oc){
      if ((oc & 3) != wv) continue;
      const int y = OY[oc], x = OX[oc];
      const int cell = y*8+x;
      float v0 = v2bg[cell*32 + cb];
      float v1 = v2bg[cell*32 + 16 + cb];
      floatx4 C0 = {v0,v0,v0,v0}, C1 = {v1,v1,v1,v1};
      #pragma unroll
      for (int dy=0;dy<3;++dy)
        #pragma unroll
        for (int dx=0;dx<3;++dx){
          const int dc = d1idx(y+dy-1, x+dx-1);
          if (dc < 0) continue;
          const int s = dy*3+dx;
          const _Float16* ap = d1 + dc*1088 + cb*68 + q*8;
          #pragma unroll
          for (int kc=0;kc<2;++kc){
            half8 a = ld8(ap + kc*32);
            C0 = MFMA16(a, bf2[s][0][kc], C0);
            C1 = MFMA16(a, bf2[s][1][kc], C1);
          }
        }
      #pragma unroll
      for (int r=0;r<4;++r){
        rm0[r] = fmaxf(rm0[r], fmaxf(C0[r],0.f));
        rm1[r] = fmaxf(rm1[r], fmaxf(C1[r],0.f));
      }
    }
    #pragma unroll
    for (int r=0;r<4;++r){
      atomicMax(&pooled[(q*4+r)*32 + cb],      __float_as_int(rm0[r]));
      atomicMax(&pooled[(q*4+r)*32 + 16 + cb], __float_as_int(rm1[r]));
    }
  }
  __syncthreads();

  for (int i=tid;i<512;i+=256){
    int bb=i>>5, c2=i&31;
    A16[bb*164 + 128 + c2] = (_Float16)__int_as_float(pooled[i]);
  }
  __syncthreads();

  {
    half8 bfF[2][5];
    #pragma unroll
    for (int nt2=0;nt2<2;++nt2)
      #pragma unroll
      for (int kc=0;kc<5;++kc)
        bfF[nt2][kc] = ld8(fus_wf + ((wv*2+nt2)*16+cb)*164 + kc*32 + q*8);
    const float fb0 = fus_b[(wv*2)*16+cb];
    const float fb1 = fus_b[(wv*2+1)*16+cb];
    floatx4 C0 = {0.f,0.f,0.f,0.f}, C1 = {0.f,0.f,0.f,0.f};
    #pragma unroll
    for (int kc=0;kc<5;++kc){
      half8 a = ld8(A16 + cb*164 + kc*32 + q*8);
      C0 = MFMA16(a, bfF[0][kc], C0);
      C1 = MFMA16(a, bfF[1][kc], C1);
    }
    #pragma unroll
    for (int r=0;r<4;++r){
      const long row = base + q*4 + r;
      fused[row*128 + (wv*2)*16+cb]   = tanh_raw(C0[r]+fb0);
      fused[row*128 + (wv*2+1)*16+cb] = tanh_raw(C1[r]+fb1);
    }
  }
}

// ---------------------------------------------------------------------------
// Decoder: 25 autoregressive steps. 16 seqs/block (M=16), 8 waves, 512 blocks.
// Gate weights prescaled by log2e (2*log2e for g); rcpf activations.
// ---------------------------------------------------------------------------
__global__ __launch_bounds__(512, 4) void dec_mfma(
    const float* __restrict__ fused,
    const float* __restrict__ w_ih, const float* __restrict__ w_hh,
    const float* __restrict__ b_ih, const float* __restrict__ b_hh,
    const float* __restrict__ out_w, const float* __restrict__ out_b,
    float* __restrict__ out)
{
  __shared__ _Float16 h_lds[2][16][136];
  __shared__ float ow_lds[2][128];
  __shared__ float pred_lds[16][2];

  const int tid  = threadIdx.x;
  const int wv   = tid >> 6;
  const int lane = tid & 63;
  const int q    = lane >> 4;
  const int cb   = lane & 15;
  const long base = (long)blockIdx.x * 16;

  for (int i=tid;i<256;i+=512) ow_lds[i>>7][i&127] = out_w[i];
  for (int i=tid;i<2048;i+=512) h_lds[0][i>>7][i&127] = (_Float16)fused[base*128 + i];
  if (tid<32) pred_lds[tid>>1][tid&1] = 0.f;

  half8 bfrag[4][4];
  float bias_g[4], wi0[4], wi1[4];
  #pragma unroll
  for (int g=0; g<4; ++g){
    const float sc = (g==2) ? L2E2 : L2E;
    const int col = g*128 + wv*16 + cb;
    bias_g[g] = (b_ih[col] + b_hh[col])*sc;
    wi0[g] = w_ih[col*2+0]*sc;
    wi1[g] = w_ih[col*2+1]*sc;
    #pragma unroll
    for (int kc=0; kc<4; ++kc){
      const float* src = w_hh + (long)col*128 + kc*32 + q*8;
      half8 f;
      #pragma unroll
      for (int j=0;j<8;++j) f[j] = (_Float16)(src[j]*sc);
      bfrag[g][kc] = f;
    }
  }
  float ob0 = out_b[0], ob1 = out_b[1];
  __syncthreads();

  const int hcol = wv*16 + cb;
  float c_reg[4] = {0,0,0,0};
  float h_new[4];

  for (int t=0; t<25; ++t){
    const _Float16 (*hr)[136] = h_lds[t&1];
    _Float16 (*hw)[136]       = h_lds[(t+1)&1];

    floatx4 acc[4];
    #pragma unroll
    for (int r=0; r<4; ++r){
      float p0 = pred_lds[q*4+r][0], p1 = pred_lds[q*4+r][1];
      #pragma unroll
      for (int g=0; g<4; ++g)
        acc[g][r] = bias_g[g] + wi0[g]*p0 + wi1[g]*p1;
    }
    #pragma unroll
    for (int kc=0; kc<4; ++kc){
      half8 a = *(const half8*)&hr[cb][kc*32 + q*8];
      #pragma unroll
      for (int g=0; g<4; ++g)
        acc[g] = MFMA16(a, bfrag[g][kc], acc[g]);
    }
    #pragma unroll
    for (int r=0; r<4; ++r){
      float ig = sig_pre(acc[0][r]);
      float fg = sig_pre(acc[1][r]);
      float gg = tanh_pre(acc[2][r]);
      float og = sig_pre(acc[3][r]);
      float c  = fg*c_reg[r] + ig*gg;
      c_reg[r] = c;
      h_new[r] = og*tanh_raw(c);
    }
    #pragma unroll
    for (int r=0; r<4; ++r) hw[q*4+r][hcol] = (_Float16)h_new[r];
    __syncthreads();    // h(t+1) visible for projection + next step
    {
      int pair = tid>>3, part = tid&7;   // 32 pairs x 8 threads = 256
      if (pair < 32){
        int m = pair>>1, oc = pair&1;
        const float* owp = ow_lds[oc];
        float v = 0.f;
        #pragma unroll
        for (int k=part*16; k<part*16+16; ++k) v += owp[k]*(float)hw[m][k];
        v += __shfl_down(v, 4, 8);
        v += __shfl_down(v, 2, 8);
        v += __shfl_down(v, 1, 8);
        if (part==0){
          v += (oc ? ob1 : ob0);
          pred_lds[m][oc] = v;
          out[(base+m)*50 + t*2 + oc] = v;
        }
      }
    }
    __syncthreads();    // pred(t) visible for next step's acc init
  }
}

// ---------------------------------------------------------------------------
extern "C" void kernel_launch(void* const* d_in, const int* in_sizes, int n_in,
                              void* d_out, int out_size, void* d_ws, size_t ws_size,
                              hipStream_t stream)
{
  (void)in_sizes; (void)n_in; (void)out_size; (void)ws_size;
  const float* target   = (const float*)d_in[0];
  const float* neigh    = (const float*)d_in[1];
  const float* enc_w_ih = (const float*)d_in[4];
  const float* enc_w_hh = (const float*)d_in[5];
  const float* enc_b_ih = (const float*)d_in[6];
  const float* enc_b_hh = (const float*)d_in[7];
  const float* nb_w_ih  = (const float*)d_in[8];
  const float* nb_w_hh  = (const float*)d_in[9];
  const float* nb_b_ih  = (const float*)d_in[10];
  const float* nb_b_hh  = (const float*)d_in[11];
  const float* w1       = (const float*)d_in[12];
  const float* b1       = (const float*)d_in[13];
  const float* w2       = (const float*)d_in[14];
  const float* b2       = (const float*)d_in[15];
  const float* fus_w    = (const float*)d_in[16];
  const float* fus_b    = (const float*)d_in[17];
  const float* dec_w_ih = (const float*)d_in[18];
  const float* dec_w_hh = (const float*)d_in[19];
  const float* dec_b_ih = (const float*)d_in[20];
  const float* dec_b_hh = (const float*)d_in[21];
  const float* out_w    = (const float*)d_in[22];
  const float* out_b    = (const float*)d_in[23];

  char* ws = (char*)d_ws;
  _Float16* h_nb16  = (_Float16*)ws;                       // 16 MB
  _Float16* h_enc16 = (_Float16*)(ws + (16u<<20));         // 2 MB
  float*    fusedp  = (float*)(ws + (18u<<20));            // 4 MB
  char* aux = ws + (22u<<20);
  _Float16* w1f    = (_Float16*)aux;                       // 152,064 B
  _Float16* w2f    = (_Float16*)(aux + 152064);            // 39,168 B
  _Float16* fus_wf = (_Float16*)(aux + 152064 + 39168);    // 41,984 B
  float*    v2bg   = (float*)(aux + 233216);               // 8,192 B
  float*    bgmaxp = (float*)(aux + 241408);               // 128 B

  prep_kernel<<<64, 256, 0, stream>>>(w1, b1, w2, b2, fus_w, w1f, w2f, fus_wf, v2bg, bgmaxp);
  lstm_all<<<4608, 512, 0, stream>>>(target, neigh,
                                     enc_w_ih, enc_w_hh, enc_b_ih, enc_b_hh,
                                     nb_w_ih, nb_w_hh, nb_b_ih, nb_b_hh,
                                     h_enc16, h_nb16);
  social_fuse<<<512, 256, 0, stream>>>(h_enc16, h_nb16, w1f, w2f, fus_wf,
                                       b1, v2bg, bgmaxp, fus_b, fusedp);
  dec_mfma<<<512, 512, 0, stream>>>(fusedp, dec_w_ih, dec_w_hh, dec_b_ih, dec_b_hh,
                                    out_w, out_b, (float*)d_out);
}